// Round 7
// baseline (4802.901 us; speedup 1.0000x reference)
//
#include <hip/hip_runtime.h>
#include <hip/hip_bf16.h>

#define T_STEPS 512
#define BATCH   256
#define DIM     256
#define HID     256
#define DEPTH   4    // X_proj ring depth (power of 2)

using bf16x8  = __attribute__((ext_vector_type(8))) __bf16;
using floatx4 = __attribute__((ext_vector_type(4))) float;
typedef unsigned long long u64;
typedef unsigned int u32;

__device__ __forceinline__ float sigf(float x)   { return 1.0f / (1.0f + __expf(-x)); }
__device__ __forceinline__ float tanh_f(float x) { return 1.0f - 2.0f / (1.0f + __expf(2.0f * x)); }

__device__ __forceinline__ bf16x8 cvt8(const float* p) {
  floatx4 a = *(const floatx4*)p;
  floatx4 b = *(const floatx4*)(p + 4);
  bf16x8 r;
  r[0]=(__bf16)a[0]; r[1]=(__bf16)a[1]; r[2]=(__bf16)a[2]; r[3]=(__bf16)a[3];
  r[4]=(__bf16)b[0]; r[5]=(__bf16)b[1]; r[6]=(__bf16)b[2]; r[7]=(__bf16)b[3];
  return r;
}
__device__ __forceinline__ u32 f2bf(float f) {
  union { float f; u32 u; } v; v.f = f;
  u32 lsb = (v.u >> 16) & 1;
  return (v.u + 0x7fff + lsb) >> 16;
}
__device__ __forceinline__ float bf2f(u32 u) {
  union { u32 u; float f; } v; v.u = u << 16; return v.f;
}

__global__ void init_ws(int* __restrict__ flg, u64* __restrict__ inbox) {
  const int idx = blockIdx.x * 256 + threadIdx.x;
  if (idx < 4096) flg[idx] = 0;
  if (idx < 65536) inbox[idx] = 0ull;
}

// 64 WGs x 512 thr. blockIdx = g + 16*role; group g = 16 batch rows.
// role 0,1: consumers (h-cols [128p,128p+128), W_hh resident 128 VGPR).
// role 2,3: producers (X_proj ring, W_ih resident).
// Consumer step: own-half MFMAs overlap packet flight; ONE blocking poll
// (self-tagging 8B packets); all secondary LLC traffic post-send.
__global__ __launch_bounds__(512, 1) void lstm_pk2(
    const float* __restrict__ x, const float* __restrict__ h0,
    const float* __restrict__ c0,
    const float* __restrict__ mask_x, const float* __restrict__ mask_h,
    const float* __restrict__ W_ih, const float* __restrict__ W_hh,
    const float* __restrict__ b_ih, const float* __restrict__ b_hh,
    const int* __restrict__ bs_g,
    float* __restrict__ out, float* __restrict__ hn_out, float* __restrict__ cn_out,
    int* __restrict__ flg, float* __restrict__ ring, u64* __restrict__ inbox) {

  const int tid  = threadIdx.x;
  const int g    = blockIdx.x & 15;
  const int role = blockIdx.x >> 4;
  const int p    = role & 1;
  const int row_base = g * 16;
  const int lane = tid & 63;
  const int w    = tid >> 6;     // wave 0..7
  const int l15  = lane & 15;
  const int l4   = lane >> 4;

  __shared__ alignas(16) __bf16 s_ab[16 * 256];   // 8 KB swizzled
  __shared__ int s_bs[T_STEPS];
  for (int i = tid; i < T_STEPS; i += 512) s_bs[i] = bs_g[i];
  __syncthreads();

  int* cons_flg_mine = flg + (g * 2 + p) * 32;          // ring backpressure
  int* prod_flg_mine = flg + 2048 + (g * 2 + p) * 32;   // ring ready
  float* ring_mine = ring + (size_t)(g * 2 + p) * (DEPTH * 8192);
  u64* inbox_mine    = inbox + (size_t)(g * 2 + p) * 2048;       // I read here
  u64* inbox_partner = inbox + (size_t)(g * 2 + (1 - p)) * 2048; // I write here

  const int c_loc = w * 16 + l15;          // local col within the 128-col half

  if (role >= 2) {
    // ================= PRODUCER (unchanged, proven) =================
    bf16x8 wih_r[4][8];
    #pragma unroll
    for (int q = 0; q < 4; ++q) {
      const size_t wr = (size_t)(q * HID + p * 128 + c_loc) * DIM;
      #pragma unroll
      for (int m = 0; m < 8; ++m) wih_r[q][m] = cvt8(W_ih + wr + m * 32 + l4 * 8);
    }
    float bias[4];
    #pragma unroll
    for (int q = 0; q < 4; ++q) {
      const int bc = q * HID + p * 128 + c_loc;
      bias[q] = b_ih[bc] + b_hh[bc];
    }
    const int srow = tid & 15, scb = (tid >> 4) * 8;
    floatx4 mx0 = *(const floatx4*)(mask_x + (row_base + srow) * DIM + scb);
    floatx4 mx1 = *(const floatx4*)(mask_x + (row_base + srow) * DIM + scb + 4);
    const int soff = (srow * 512 + scb * 2) ^ ((srow & 7) << 4);

    for (int t = 0; t < T_STEPS; ++t) {
      if (s_bs[t] <= row_base) break;
      if (t >= DEPTH) {
        const int tgt = t - (DEPTH - 1);
        while (__hip_atomic_load(cons_flg_mine, __ATOMIC_RELAXED, __HIP_MEMORY_SCOPE_AGENT) < tgt) {}
      }
      const float* xp = x + ((size_t)t * BATCH + row_base + srow) * DIM + scb;
      floatx4 xa = *(const floatx4*)xp;
      floatx4 xb = *(const floatx4*)(xp + 4);
      bf16x8 xv;
      #pragma unroll
      for (int e = 0; e < 4; ++e) { xv[e] = (__bf16)(xa[e] * mx0[e]); xv[4 + e] = (__bf16)(xb[e] * mx1[e]); }
      *(bf16x8*)((char*)s_ab + soff) = xv;
      asm volatile("s_waitcnt lgkmcnt(0)" ::: "memory");
      __builtin_amdgcn_s_barrier();

      floatx4 a0, a1, a2, a3;
      a0 = a1 = a2 = a3 = (floatx4)(0.0f);
      #pragma unroll
      for (int m = 0; m < 8; ++m) {
        const int ab = (l15 * 512 + l4 * 16 + m * 64) ^ ((l15 & 7) << 4);
        bf16x8 ax = *(const bf16x8*)((const char*)s_ab + ab);
        a0 = __builtin_amdgcn_mfma_f32_16x16x32_bf16(ax, wih_r[0][m], a0, 0, 0, 0);
        a1 = __builtin_amdgcn_mfma_f32_16x16x32_bf16(ax, wih_r[1][m], a1, 0, 0, 0);
        a2 = __builtin_amdgcn_mfma_f32_16x16x32_bf16(ax, wih_r[2][m], a2, 0, 0, 0);
        a3 = __builtin_amdgcn_mfma_f32_16x16x32_bf16(ax, wih_r[3][m], a3, 0, 0, 0);
      }
      float* rs = ring_mine + (size_t)(t & (DEPTH - 1)) * 8192;
      #pragma unroll
      for (int e = 0; e < 4; ++e) {
        const int rb = (l4 * 4 + e) * 4;
        __hip_atomic_store(rs + (rb + 0) * 128 + c_loc, a0[e] + bias[0], __ATOMIC_RELAXED, __HIP_MEMORY_SCOPE_AGENT);
        __hip_atomic_store(rs + (rb + 1) * 128 + c_loc, a1[e] + bias[1], __ATOMIC_RELAXED, __HIP_MEMORY_SCOPE_AGENT);
        __hip_atomic_store(rs + (rb + 2) * 128 + c_loc, a2[e] + bias[2], __ATOMIC_RELAXED, __HIP_MEMORY_SCOPE_AGENT);
        __hip_atomic_store(rs + (rb + 3) * 128 + c_loc, a3[e] + bias[3], __ATOMIC_RELAXED, __HIP_MEMORY_SCOPE_AGENT);
      }
      asm volatile("s_waitcnt vmcnt(0)" ::: "memory");
      __builtin_amdgcn_s_barrier();
      if (tid == 0)
        __hip_atomic_store(prod_flg_mine, t + 1, __ATOMIC_RELAXED, __HIP_MEMORY_SCOPE_AGENT);
    }
    return;
  }

  // ================= CONSUMER =================
  const int c_own = p * 128 + c_loc;
  bf16x8 whh_r[4][8];   // absolute K index m: k = m*32
  #pragma unroll
  for (int q = 0; q < 4; ++q) {
    const size_t wr = (size_t)(q * HID + c_own) * HID;
    #pragma unroll
    for (int m = 0; m < 8; ++m) whh_r[q][m] = cvt8(W_hh + wr + m * 32 + l4 * 8);
  }
  float mh_c[4], h_[4], c_[4];
  #pragma unroll
  for (int e = 0; e < 4; ++e) {
    const int grow = row_base + l4 * 4 + e;
    mh_c[e] = mask_h[grow * HID + c_own];
    h_[e]   = h0[grow * HID + c_own];
    c_[e]   = c0[grow * HID + c_own];
  }
  // receiver map: thread -> (partner col sc_loc, rows rq*4..rq*4+3)
  const int sc_loc = tid >> 2;
  const int rq     = tid & 3;
  const int c_gs   = (1 - p) * 128 + sc_loc;
  float mh_s[4];
  #pragma unroll
  for (int e = 0; e < 4; ++e) mh_s[e] = mask_h[(row_base + rq * 4 + e) * HID + c_gs];

  const int mo = p * 4;          // own-half K block (k = [p*128, p*128+128))
  const int mp = (1 - p) * 4;    // partner-half K block

  // prologue: stage own h(0); preload X_proj(0)
  #pragma unroll
  for (int e = 0; e < 4; ++e) {
    const int r = l4 * 4 + e;
    const int off = (r * 512 + c_own * 2) ^ ((r & 7) << 4);
    *(__bf16*)((char*)s_ab + off) = (__bf16)(h_[e] * mh_c[e]);
  }
  while (__hip_atomic_load(prod_flg_mine, __ATOMIC_RELAXED, __HIP_MEMORY_SCOPE_AGENT) < 1) {}
  asm volatile("" ::: "memory");
  float xp_c[16];
  #pragma unroll
  for (int e = 0; e < 4; ++e)
    #pragma unroll
    for (int q = 0; q < 4; ++q)
      xp_c[e * 4 + q] = __hip_atomic_load(ring_mine + ((l4 * 4 + e) * 4 + q) * 128 + c_loc,
                                          __ATOMIC_RELAXED, __HIP_MEMORY_SCOPE_AGENT);
  asm volatile("s_waitcnt lgkmcnt(0)" ::: "memory");
  __builtin_amdgcn_s_barrier();

  for (int t = 0; t < T_STEPS; ++t) {
    const int bszt = s_bs[t];
    if (bszt <= row_base) {
      #pragma unroll
      for (int e = 0; e < 4; ++e)
        out[(size_t)t * (BATCH * HID) + (row_base + l4 * 4 + e) * HID + c_own] = 0.0f;
      continue;
    }
    const bool act_n = (t + 1 < T_STEPS) && (s_bs[t + 1] > row_base);

    // C: own-half MFMAs (K=128) — overlap partner packet flight
    floatx4 a0, a1, a2, a3;
    a0 = a1 = a2 = a3 = (floatx4)(0.0f);
    #pragma unroll
    for (int i = 0; i < 4; ++i) {
      const int m = mo + i;
      const int ab = (l15 * 512 + l4 * 16 + m * 64) ^ ((l15 & 7) << 4);
      bf16x8 ah = *(const bf16x8*)((const char*)s_ab + ab);
      a0 = __builtin_amdgcn_mfma_f32_16x16x32_bf16(ah, whh_r[0][m], a0, 0, 0, 0);
      a1 = __builtin_amdgcn_mfma_f32_16x16x32_bf16(ah, whh_r[1][m], a1, 0, 0, 0);
      a2 = __builtin_amdgcn_mfma_f32_16x16x32_bf16(ah, whh_r[2][m], a2, 0, 0, 0);
      a3 = __builtin_amdgcn_mfma_f32_16x16x32_bf16(ah, whh_r[3][m], a3, 0, 0, 0);
    }

    // D/E: partner half — the ONLY blocking wait
    if (t == 0) {
      #pragma unroll
      for (int e = 0; e < 4; ++e) {
        const int r = rq * 4 + e;
        const float hv = h0[(row_base + r) * HID + c_gs] * mh_s[e];
        const int off = (r * 512 + c_gs * 2) ^ ((r & 7) << 4);
        *(__bf16*)((char*)s_ab + off) = (__bf16)hv;
      }
    } else {
      const u64* ib = inbox_mine + (size_t)(t & 1) * 1024 + sc_loc * 8 + rq * 2;
      u64 pk0, pk1;
      do {
        pk0 = __hip_atomic_load(ib,     __ATOMIC_RELAXED, __HIP_MEMORY_SCOPE_AGENT);
        pk1 = __hip_atomic_load(ib + 1, __ATOMIC_RELAXED, __HIP_MEMORY_SCOPE_AGENT);
      } while (!__all((int)(((u32)pk0 == (u32)t) && ((u32)pk1 == (u32)t))));
      float hv[4];
      hv[0] = bf2f((u32)(pk0 >> 32) & 0xffffu) * mh_s[0];
      hv[1] = bf2f((u32)(pk0 >> 48))           * mh_s[1];
      hv[2] = bf2f((u32)(pk1 >> 32) & 0xffffu) * mh_s[2];
      hv[3] = bf2f((u32)(pk1 >> 48))           * mh_s[3];
      #pragma unroll
      for (int e = 0; e < 4; ++e) {
        const int r = rq * 4 + e;
        const int off = (r * 512 + c_gs * 2) ^ ((r & 7) << 4);
        *(__bf16*)((char*)s_ab + off) = (__bf16)hv[e];
      }
    }
    asm volatile("s_waitcnt lgkmcnt(0)" ::: "memory");
    __builtin_amdgcn_s_barrier();   // F: partner region visible

    // G: partner-half MFMAs (K=128)
    #pragma unroll
    for (int i = 0; i < 4; ++i) {
      const int m = mp + i;
      const int ab = (l15 * 512 + l4 * 16 + m * 64) ^ ((l15 & 7) << 4);
      bf16x8 ah = *(const bf16x8*)((const char*)s_ab + ab);
      a0 = __builtin_amdgcn_mfma_f32_16x16x32_bf16(ah, whh_r[0][m], a0, 0, 0, 0);
      a1 = __builtin_amdgcn_mfma_f32_16x16x32_bf16(ah, whh_r[1][m], a1, 0, 0, 0);
      a2 = __builtin_amdgcn_mfma_f32_16x16x32_bf16(ah, whh_r[2][m], a2, 0, 0, 0);
      a3 = __builtin_amdgcn_mfma_f32_16x16x32_bf16(ah, whh_r[3][m], a3, 0, 0, 0);
    }

    // H: cell (C layout: row = l4*4+e, col = l15 -> c_own)
    float o_[4];
    #pragma unroll
    for (int e = 0; e < 4; ++e) {
      const bool ract = (row_base + l4 * 4 + e) < bszt;
      const float iv = sigf(a0[e] + xp_c[e * 4 + 0]);
      const float fv = sigf(a1[e] + xp_c[e * 4 + 1]);
      const float gv = tanh_f(a2[e] + xp_c[e * 4 + 2]);
      const float ov = sigf(a3[e] + xp_c[e * 4 + 3]);
      const float cc = fv * c_[e] + iv * gv;
      const float hh = ov * tanh_f(cc);
      if (ract) { c_[e] = cc; h_[e] = hh; }
      o_[e] = ract ? hh : 0.0f;
    }

    // SEND FIRST: partner latency starts now
    if (act_n) {
      u64* ob = inbox_partner + (size_t)((t + 1) & 1) * 1024 + c_loc * 8 + l4 * 2;
      const u64 tag = (u32)(t + 1);
      u64 w0 = tag | ((u64)f2bf(h_[0]) << 32) | ((u64)f2bf(h_[1]) << 48);
      u64 w1 = tag | ((u64)f2bf(h_[2]) << 32) | ((u64)f2bf(h_[3]) << 48);
      __hip_atomic_store(ob,     w0, __ATOMIC_RELAXED, __HIP_MEMORY_SCOPE_AGENT);
      __hip_atomic_store(ob + 1, w1, __ATOMIC_RELAXED, __HIP_MEMORY_SCOPE_AGENT);
    }

    // post-send (off critical path): own-h staging, out, flags, X_proj(t+1)
    if (act_n) {
      #pragma unroll
      for (int e = 0; e < 4; ++e) {
        const int r = l4 * 4 + e;
        const int off = (r * 512 + c_own * 2) ^ ((r & 7) << 4);
        *(__bf16*)((char*)s_ab + off) = (__bf16)(h_[e] * mh_c[e]);
      }
    }
    #pragma unroll
    for (int e = 0; e < 4; ++e)
      out[(size_t)t * (BATCH * HID) + (row_base + l4 * 4 + e) * HID + c_own] = o_[e];

    if (act_n) {
      if (tid == 0)
        __hip_atomic_store(cons_flg_mine, t + 1, __ATOMIC_RELAXED, __HIP_MEMORY_SCOPE_AGENT);
      while (__hip_atomic_load(prod_flg_mine, __ATOMIC_RELAXED, __HIP_MEMORY_SCOPE_AGENT) < t + 2) {}
      asm volatile("" ::: "memory");
      const float* rs = ring_mine + (size_t)((t + 1) & (DEPTH - 1)) * 8192;
      #pragma unroll
      for (int e = 0; e < 4; ++e)
        #pragma unroll
        for (int q = 0; q < 4; ++q)
          xp_c[e * 4 + q] = __hip_atomic_load(rs + ((l4 * 4 + e) * 4 + q) * 128 + c_loc,
                                              __ATOMIC_RELAXED, __HIP_MEMORY_SCOPE_AGENT);
    }

    // I: own-h(t+1) visible for next C; WAR-protect s_ab
    asm volatile("s_waitcnt lgkmcnt(0)" ::: "memory");
    __builtin_amdgcn_s_barrier();
  }

  // epilogue
  #pragma unroll
  for (int e = 0; e < 4; ++e) {
    const int grow = row_base + l4 * 4 + e;
    hn_out[grow * HID + c_own] = h_[e];
    cn_out[grow * HID + c_own] = c_[e];
  }
}

extern "C" void kernel_launch(void* const* d_in, const int* in_sizes, int n_in,
                              void* d_out, int out_size, void* d_ws, size_t ws_size,
                              hipStream_t stream) {
  const float* x      = (const float*)d_in[0];
  const float* h0     = (const float*)d_in[1];
  const float* c0     = (const float*)d_in[2];
  const float* mask_x = (const float*)d_in[3];
  const float* mask_h = (const float*)d_in[4];
  const float* W_ih   = (const float*)d_in[5];
  const float* W_hh   = (const float*)d_in[6];
  const float* b_ih   = (const float*)d_in[7];
  const float* b_hh   = (const float*)d_in[8];
  const int*   bs     = (const int*)d_in[9];

  float* out = (float*)d_out;
  float* hn  = out + (size_t)T_STEPS * BATCH * HID;
  float* cn  = hn + (size_t)BATCH * HID;

  int* flg  = (int*)d_ws;                                   // 16 KB flags
  float* ring = (float*)((char*)d_ws + 16384);              // 4 MB X_proj ring
  u64* inbox = (u64*)((char*)d_ws + 16384 + 4194304);       // 512 KB packet inboxes

  init_ws<<<256, 256, 0, stream>>>(flg, inbox);
  lstm_pk2<<<64, 512, 0, stream>>>(x, h0, c0, mask_x, mask_h, W_ih, W_hh,
                                   b_ih, b_hh, bs, out, hn, cn, flg, ring, inbox);
}

// Round 8
// 1640.300 us; speedup vs baseline: 2.9281x; 2.9281x over previous
//
#include <hip/hip_runtime.h>
#include <hip/hip_bf16.h>

#define T_STEPS 512
#define BATCH   256
#define DIM     256
#define HID     256
#define DEPTH   4    // X_proj ring depth (power of 2)

using bf16x8  = __attribute__((ext_vector_type(8))) __bf16;
using floatx4 = __attribute__((ext_vector_type(4))) float;
typedef unsigned long long u64;
typedef unsigned int u32;

__device__ __forceinline__ float sigf(float x)   { return 1.0f / (1.0f + __expf(-x)); }
__device__ __forceinline__ float tanh_f(float x) { return 1.0f - 2.0f / (1.0f + __expf(2.0f * x)); }

__device__ __forceinline__ bf16x8 cvt8(const float* p) {
  floatx4 a = *(const floatx4*)p;
  floatx4 b = *(const floatx4*)(p + 4);
  bf16x8 r;
  r[0]=(__bf16)a[0]; r[1]=(__bf16)a[1]; r[2]=(__bf16)a[2]; r[3]=(__bf16)a[3];
  r[4]=(__bf16)b[0]; r[5]=(__bf16)b[1]; r[6]=(__bf16)b[2]; r[7]=(__bf16)b[3];
  return r;
}
__device__ __forceinline__ u32 f2bf(float f) {
  union { float f; u32 u; } v; v.f = f;
  u32 lsb = (v.u >> 16) & 1;
  return (v.u + 0x7fff + lsb) >> 16;
}
__device__ __forceinline__ float bf2f(u32 u) {
  union { u32 u; float f; } v; v.u = u << 16; return v.f;
}

__global__ void init_ws(int* __restrict__ flg, u64* __restrict__ inbox) {
  const int idx = blockIdx.x * 256 + threadIdx.x;
  if (idx < 4096) flg[idx] = 0;
  if (idx < 65536) inbox[idx] = 0ull;
}

// 64 WGs x 512 thr. blockIdx = g + 16*role; group g = 16 batch rows.
// role 0,1: consumers (h-cols [128p,128p+128), W_hh resident; own-half K in
// whh_r[q][0..3], partner half in [4..7] -> ALL indices compile-time).
// role 2,3: producers (X_proj ring, W_ih resident).
// Consumer step: own-half MFMAs overlap packet flight; ONE blocking poll
// (self-tagging 8B packets); all secondary LLC traffic post-send.
__global__ __launch_bounds__(512, 1) void lstm_pk3(
    const float* __restrict__ x, const float* __restrict__ h0,
    const float* __restrict__ c0,
    const float* __restrict__ mask_x, const float* __restrict__ mask_h,
    const float* __restrict__ W_ih, const float* __restrict__ W_hh,
    const float* __restrict__ b_ih, const float* __restrict__ b_hh,
    const int* __restrict__ bs_g,
    float* __restrict__ out, float* __restrict__ hn_out, float* __restrict__ cn_out,
    int* __restrict__ flg, float* __restrict__ ring, u64* __restrict__ inbox) {

  const int tid  = threadIdx.x;
  const int g    = blockIdx.x & 15;
  const int role = blockIdx.x >> 4;
  const int p    = role & 1;
  const int row_base = g * 16;
  const int lane = tid & 63;
  const int w    = tid >> 6;     // wave 0..7
  const int l15  = lane & 15;
  const int l4   = lane >> 4;

  __shared__ alignas(16) __bf16 s_ab[16 * 256];   // 8 KB swizzled
  __shared__ int s_bs[T_STEPS];
  for (int i = tid; i < T_STEPS; i += 512) s_bs[i] = bs_g[i];
  __syncthreads();

  int* cons_flg_mine = flg + (g * 2 + p) * 32;          // ring backpressure
  int* prod_flg_mine = flg + 2048 + (g * 2 + p) * 32;   // ring ready
  float* ring_mine = ring + (size_t)(g * 2 + p) * (DEPTH * 8192);
  u64* inbox_mine    = inbox + (size_t)(g * 2 + p) * 2048;       // I read here
  u64* inbox_partner = inbox + (size_t)(g * 2 + (1 - p)) * 2048; // I write here

  const int c_loc = w * 16 + l15;          // local col within the 128-col half

  if (role >= 2) {
    // ================= PRODUCER (unchanged, proven) =================
    bf16x8 wih_r[4][8];
    #pragma unroll
    for (int q = 0; q < 4; ++q) {
      const size_t wr = (size_t)(q * HID + p * 128 + c_loc) * DIM;
      #pragma unroll
      for (int m = 0; m < 8; ++m) wih_r[q][m] = cvt8(W_ih + wr + m * 32 + l4 * 8);
    }
    float bias[4];
    #pragma unroll
    for (int q = 0; q < 4; ++q) {
      const int bc = q * HID + p * 128 + c_loc;
      bias[q] = b_ih[bc] + b_hh[bc];
    }
    const int srow = tid & 15, scb = (tid >> 4) * 8;
    floatx4 mx0 = *(const floatx4*)(mask_x + (row_base + srow) * DIM + scb);
    floatx4 mx1 = *(const floatx4*)(mask_x + (row_base + srow) * DIM + scb + 4);
    const int soff = (srow * 512 + scb * 2) ^ ((srow & 7) << 4);

    for (int t = 0; t < T_STEPS; ++t) {
      if (s_bs[t] <= row_base) break;
      if (t >= DEPTH) {
        const int tgt = t - (DEPTH - 1);
        while (__hip_atomic_load(cons_flg_mine, __ATOMIC_RELAXED, __HIP_MEMORY_SCOPE_AGENT) < tgt) {}
      }
      const float* xp = x + ((size_t)t * BATCH + row_base + srow) * DIM + scb;
      floatx4 xa = *(const floatx4*)xp;
      floatx4 xb = *(const floatx4*)(xp + 4);
      bf16x8 xv;
      #pragma unroll
      for (int e = 0; e < 4; ++e) { xv[e] = (__bf16)(xa[e] * mx0[e]); xv[4 + e] = (__bf16)(xb[e] * mx1[e]); }
      *(bf16x8*)((char*)s_ab + soff) = xv;
      asm volatile("s_waitcnt lgkmcnt(0)" ::: "memory");
      __builtin_amdgcn_s_barrier();

      floatx4 a0, a1, a2, a3;
      a0 = a1 = a2 = a3 = (floatx4)(0.0f);
      #pragma unroll
      for (int m = 0; m < 8; ++m) {
        const int ab = (l15 * 512 + l4 * 16 + m * 64) ^ ((l15 & 7) << 4);
        bf16x8 ax = *(const bf16x8*)((const char*)s_ab + ab);
        a0 = __builtin_amdgcn_mfma_f32_16x16x32_bf16(ax, wih_r[0][m], a0, 0, 0, 0);
        a1 = __builtin_amdgcn_mfma_f32_16x16x32_bf16(ax, wih_r[1][m], a1, 0, 0, 0);
        a2 = __builtin_amdgcn_mfma_f32_16x16x32_bf16(ax, wih_r[2][m], a2, 0, 0, 0);
        a3 = __builtin_amdgcn_mfma_f32_16x16x32_bf16(ax, wih_r[3][m], a3, 0, 0, 0);
      }
      float* rs = ring_mine + (size_t)(t & (DEPTH - 1)) * 8192;
      #pragma unroll
      for (int e = 0; e < 4; ++e) {
        const int rb = (l4 * 4 + e) * 4;
        __hip_atomic_store(rs + (rb + 0) * 128 + c_loc, a0[e] + bias[0], __ATOMIC_RELAXED, __HIP_MEMORY_SCOPE_AGENT);
        __hip_atomic_store(rs + (rb + 1) * 128 + c_loc, a1[e] + bias[1], __ATOMIC_RELAXED, __HIP_MEMORY_SCOPE_AGENT);
        __hip_atomic_store(rs + (rb + 2) * 128 + c_loc, a2[e] + bias[2], __ATOMIC_RELAXED, __HIP_MEMORY_SCOPE_AGENT);
        __hip_atomic_store(rs + (rb + 3) * 128 + c_loc, a3[e] + bias[3], __ATOMIC_RELAXED, __HIP_MEMORY_SCOPE_AGENT);
      }
      asm volatile("s_waitcnt vmcnt(0)" ::: "memory");
      __builtin_amdgcn_s_barrier();
      if (tid == 0)
        __hip_atomic_store(prod_flg_mine, t + 1, __ATOMIC_RELAXED, __HIP_MEMORY_SCOPE_AGENT);
    }
    return;
  }

  // ================= CONSUMER =================
  const int c_own = p * 128 + c_loc;
  // Weight layout: [q][0..3] = OWN K-half (k in [p*128,p*128+128)),
  //                [q][4..7] = PARTNER K-half. All compute indices static.
  bf16x8 whh_r[4][8];
  #pragma unroll
  for (int q = 0; q < 4; ++q) {
    const size_t wr = (size_t)(q * HID + c_own) * HID;
    const float* wown = W_hh + wr + p * 128;        // runtime ADDRESS, fine
    const float* wpar = W_hh + wr + (1 - p) * 128;
    #pragma unroll
    for (int i = 0; i < 4; ++i) {
      whh_r[q][i]     = cvt8(wown + i * 32 + l4 * 8);
      whh_r[q][4 + i] = cvt8(wpar + i * 32 + l4 * 8);
    }
  }
  float mh_c[4], h_[4], c_[4];
  #pragma unroll
  for (int e = 0; e < 4; ++e) {
    const int grow = row_base + l4 * 4 + e;
    mh_c[e] = mask_h[grow * HID + c_own];
    h_[e]   = h0[grow * HID + c_own];
    c_[e]   = c0[grow * HID + c_own];
  }
  // receiver map: thread -> (partner col sc_loc, rows rq*4..rq*4+3)
  const int sc_loc = tid >> 2;
  const int rq     = tid & 3;
  const int c_gs   = (1 - p) * 128 + sc_loc;
  float mh_s[4];
  #pragma unroll
  for (int e = 0; e < 4; ++e) mh_s[e] = mask_h[(row_base + rq * 4 + e) * HID + c_gs];

  // LDS byte offsets for the two K-halves (runtime scalar adds, not indices)
  const int abase   = l15 * 512 + l4 * 16;
  const int own_off = p * 256;          // own K-half starts at k=p*128 -> bytes p*256
  const int par_off = (1 - p) * 256;

  // prologue: stage own h(0); preload X_proj(0)
  #pragma unroll
  for (int e = 0; e < 4; ++e) {
    const int r = l4 * 4 + e;
    const int off = (r * 512 + c_own * 2) ^ ((r & 7) << 4);
    *(__bf16*)((char*)s_ab + off) = (__bf16)(h_[e] * mh_c[e]);
  }
  while (__hip_atomic_load(prod_flg_mine, __ATOMIC_RELAXED, __HIP_MEMORY_SCOPE_AGENT) < 1) {}
  asm volatile("" ::: "memory");
  float xp_c[16];
  #pragma unroll
  for (int e = 0; e < 4; ++e)
    #pragma unroll
    for (int q = 0; q < 4; ++q)
      xp_c[e * 4 + q] = __hip_atomic_load(ring_mine + ((l4 * 4 + e) * 4 + q) * 128 + c_loc,
                                          __ATOMIC_RELAXED, __HIP_MEMORY_SCOPE_AGENT);
  asm volatile("s_waitcnt lgkmcnt(0)" ::: "memory");
  __builtin_amdgcn_s_barrier();

  for (int t = 0; t < T_STEPS; ++t) {
    const int bszt = s_bs[t];
    if (bszt <= row_base) {
      #pragma unroll
      for (int e = 0; e < 4; ++e)
        out[(size_t)t * (BATCH * HID) + (row_base + l4 * 4 + e) * HID + c_own] = 0.0f;
      continue;
    }
    const bool act_n = (t + 1 < T_STEPS) && (s_bs[t + 1] > row_base);

    // C: own-half MFMAs (K=128, static indices 0..3) — overlap packet flight
    floatx4 a0, a1, a2, a3;
    a0 = a1 = a2 = a3 = (floatx4)(0.0f);
    #pragma unroll
    for (int i = 0; i < 4; ++i) {
      const int ab = ((abase + own_off + i * 64)) ^ ((l15 & 7) << 4);
      bf16x8 ah = *(const bf16x8*)((const char*)s_ab + ab);
      a0 = __builtin_amdgcn_mfma_f32_16x16x32_bf16(ah, whh_r[0][i], a0, 0, 0, 0);
      a1 = __builtin_amdgcn_mfma_f32_16x16x32_bf16(ah, whh_r[1][i], a1, 0, 0, 0);
      a2 = __builtin_amdgcn_mfma_f32_16x16x32_bf16(ah, whh_r[2][i], a2, 0, 0, 0);
      a3 = __builtin_amdgcn_mfma_f32_16x16x32_bf16(ah, whh_r[3][i], a3, 0, 0, 0);
    }

    // D/E: partner half — the ONLY blocking wait
    if (t == 0) {
      #pragma unroll
      for (int e = 0; e < 4; ++e) {
        const int r = rq * 4 + e;
        const float hv = h0[(row_base + r) * HID + c_gs] * mh_s[e];
        const int off = (r * 512 + c_gs * 2) ^ ((r & 7) << 4);
        *(__bf16*)((char*)s_ab + off) = (__bf16)hv;
      }
    } else {
      const u64* ib = inbox_mine + (size_t)(t & 1) * 1024 + sc_loc * 8 + rq * 2;
      u64 pk0, pk1;
      do {
        pk0 = __hip_atomic_load(ib,     __ATOMIC_RELAXED, __HIP_MEMORY_SCOPE_AGENT);
        pk1 = __hip_atomic_load(ib + 1, __ATOMIC_RELAXED, __HIP_MEMORY_SCOPE_AGENT);
      } while (!__all((int)(((u32)pk0 == (u32)t) && ((u32)pk1 == (u32)t))));
      float hv[4];
      hv[0] = bf2f((u32)(pk0 >> 32) & 0xffffu) * mh_s[0];
      hv[1] = bf2f((u32)(pk0 >> 48))           * mh_s[1];
      hv[2] = bf2f((u32)(pk1 >> 32) & 0xffffu) * mh_s[2];
      hv[3] = bf2f((u32)(pk1 >> 48))           * mh_s[3];
      #pragma unroll
      for (int e = 0; e < 4; ++e) {
        const int r = rq * 4 + e;
        const int off = (r * 512 + c_gs * 2) ^ ((r & 7) << 4);
        *(__bf16*)((char*)s_ab + off) = (__bf16)hv[e];
      }
    }
    asm volatile("s_waitcnt lgkmcnt(0)" ::: "memory");
    __builtin_amdgcn_s_barrier();   // F: partner region visible

    // G: partner-half MFMAs (K=128, static indices 4..7)
    #pragma unroll
    for (int i = 0; i < 4; ++i) {
      const int ab = ((abase + par_off + i * 64)) ^ ((l15 & 7) << 4);
      bf16x8 ah = *(const bf16x8*)((const char*)s_ab + ab);
      a0 = __builtin_amdgcn_mfma_f32_16x16x32_bf16(ah, whh_r[0][4 + i], a0, 0, 0, 0);
      a1 = __builtin_amdgcn_mfma_f32_16x16x32_bf16(ah, whh_r[1][4 + i], a1, 0, 0, 0);
      a2 = __builtin_amdgcn_mfma_f32_16x16x32_bf16(ah, whh_r[2][4 + i], a2, 0, 0, 0);
      a3 = __builtin_amdgcn_mfma_f32_16x16x32_bf16(ah, whh_r[3][4 + i], a3, 0, 0, 0);
    }

    // H: cell (C layout: row = l4*4+e, col = l15 -> c_own)
    float o_[4];
    #pragma unroll
    for (int e = 0; e < 4; ++e) {
      const bool ract = (row_base + l4 * 4 + e) < bszt;
      const float iv = sigf(a0[e] + xp_c[e * 4 + 0]);
      const float fv = sigf(a1[e] + xp_c[e * 4 + 1]);
      const float gv = tanh_f(a2[e] + xp_c[e * 4 + 2]);
      const float ov = sigf(a3[e] + xp_c[e * 4 + 3]);
      const float cc = fv * c_[e] + iv * gv;
      const float hh = ov * tanh_f(cc);
      if (ract) { c_[e] = cc; h_[e] = hh; }
      o_[e] = ract ? hh : 0.0f;
    }

    // SEND FIRST: partner latency starts now
    if (act_n) {
      u64* ob = inbox_partner + (size_t)((t + 1) & 1) * 1024 + c_loc * 8 + l4 * 2;
      const u64 tag = (u32)(t + 1);
      u64 w0 = tag | ((u64)f2bf(h_[0]) << 32) | ((u64)f2bf(h_[1]) << 48);
      u64 w1 = tag | ((u64)f2bf(h_[2]) << 32) | ((u64)f2bf(h_[3]) << 48);
      __hip_atomic_store(ob,     w0, __ATOMIC_RELAXED, __HIP_MEMORY_SCOPE_AGENT);
      __hip_atomic_store(ob + 1, w1, __ATOMIC_RELAXED, __HIP_MEMORY_SCOPE_AGENT);
    }

    // post-send (off critical path): own-h staging, out, flags, X_proj(t+1)
    if (act_n) {
      #pragma unroll
      for (int e = 0; e < 4; ++e) {
        const int r = l4 * 4 + e;
        const int off = (r * 512 + c_own * 2) ^ ((r & 7) << 4);
        *(__bf16*)((char*)s_ab + off) = (__bf16)(h_[e] * mh_c[e]);
      }
    }
    #pragma unroll
    for (int e = 0; e < 4; ++e)
      out[(size_t)t * (BATCH * HID) + (row_base + l4 * 4 + e) * HID + c_own] = o_[e];

    if (act_n) {
      if (tid == 0)
        __hip_atomic_store(cons_flg_mine, t + 1, __ATOMIC_RELAXED, __HIP_MEMORY_SCOPE_AGENT);
      while (__hip_atomic_load(prod_flg_mine, __ATOMIC_RELAXED, __HIP_MEMORY_SCOPE_AGENT) < t + 2) {}
      asm volatile("" ::: "memory");
      const float* rs = ring_mine + (size_t)((t + 1) & (DEPTH - 1)) * 8192;
      #pragma unroll
      for (int e = 0; e < 4; ++e)
        #pragma unroll
        for (int q = 0; q < 4; ++q)
          xp_c[e * 4 + q] = __hip_atomic_load(rs + ((l4 * 4 + e) * 4 + q) * 128 + c_loc,
                                              __ATOMIC_RELAXED, __HIP_MEMORY_SCOPE_AGENT);
    }

    // I: own-h(t+1) visible for next C; WAR-protect s_ab
    asm volatile("s_waitcnt lgkmcnt(0)" ::: "memory");
    __builtin_amdgcn_s_barrier();
  }

  // epilogue
  #pragma unroll
  for (int e = 0; e < 4; ++e) {
    const int grow = row_base + l4 * 4 + e;
    hn_out[grow * HID + c_own] = h_[e];
    cn_out[grow * HID + c_own] = c_[e];
  }
}

extern "C" void kernel_launch(void* const* d_in, const int* in_sizes, int n_in,
                              void* d_out, int out_size, void* d_ws, size_t ws_size,
                              hipStream_t stream) {
  const float* x      = (const float*)d_in[0];
  const float* h0     = (const float*)d_in[1];
  const float* c0     = (const float*)d_in[2];
  const float* mask_x = (const float*)d_in[3];
  const float* mask_h = (const float*)d_in[4];
  const float* W_ih   = (const float*)d_in[5];
  const float* W_hh   = (const float*)d_in[6];
  const float* b_ih   = (const float*)d_in[7];
  const float* b_hh   = (const float*)d_in[8];
  const int*   bs     = (const int*)d_in[9];

  float* out = (float*)d_out;
  float* hn  = out + (size_t)T_STEPS * BATCH * HID;
  float* cn  = hn + (size_t)BATCH * HID;

  int* flg  = (int*)d_ws;                                   // 16 KB flags
  float* ring = (float*)((char*)d_ws + 16384);              // 4 MB X_proj ring
  u64* inbox = (u64*)((char*)d_ws + 16384 + 4194304);       // 512 KB packet inboxes

  init_ws<<<256, 256, 0, stream>>>(flg, inbox);
  lstm_pk3<<<64, 512, 0, stream>>>(x, h0, c0, mask_x, mask_h, W_ih, W_hh,
                                   b_ih, b_hh, bs, out, hn, cn, flg, ring, inbox);
}